// Round 6
// baseline (58.062 us; speedup 1.0000x reference)
//
#include <hip/hip_runtime.h>
#include <math.h>

#define EPSF 1e-20f
#define NEG_INF (-INFINITY)

__device__ __forceinline__ float softplusf(float x) {
    return fmaxf(x, 0.0f) + log1pf(expf(-fabsf(x)));
}
// fast reciprocal (v_rcp_f32) — ONLY for tolerance-protected epilogue math,
// never for argmax comparison values.
__device__ __forceinline__ float fastrcp(float x) {
    return __builtin_amdgcn_rcpf(x);
}

// One block = 64x64 output tile of one (b,c) plane; 1024 blocks x 512 threads.
// Stage BC: per-thread x-cell PAIR (round-2 k1 body verbatim): dual argmax over
//           shared 4x6 window + propagation math -> lx LDS. No W stage.
// Stage D : 4-tap transposed depthwise conv + fused epilogue (round-5 verbatim).
__global__ __launch_bounds__(512, 8) void fused_sndeconv(
    const float* __restrict__ d, const float* __restrict__ cd,
    const float* __restrict__ s, const float* __restrict__ cs,
    const float* __restrict__ w_s_from_d, const float* __restrict__ w_prop,
    const float* __restrict__ spatial_weight, const float* __restrict__ bias,
    float* __restrict__ s_out, float* __restrict__ cs_out)
{
    __shared__ float lx1[34][40];        // x1 tile, L' = n - nB0 + 1 in [1..36]; 5.4 KB
    __shared__ float lx2[34][40];        // x2 tile; 5.4 KB
    __shared__ float sws[16];

    const int tid = threadIdx.x;
    const int blk = blockIdx.x;
    const int bc  = blk >> 4;            // plane 0..63
    const int tl  = blk & 15;
    const int ty  = tl >> 2;             // 0..3 (64-row bands)
    const int tx  = tl & 3;              // 0..3 (64-col bands)
    const int c   = bc & 15;

    const int ib  = ty << 6;             // output row base
    const int jb  = tx << 6;             // output col base
    const int mB  = (ib >> 1) - 1;       // x-row base (34 rows: mB..mB+33)
    const int nB0 = (jb >> 1) - 2;       // even x-col pair base

    if (tid < 16) sws[tid] = softplusf(spatial_weight[c * 16 + tid]);

    const float* dp  = d  + (size_t)bc * 65536;
    const float* cdp = cd + (size_t)bc * 65536;
    const float* sp  = s  + (size_t)bc * 16384;
    const float* csp = cs + (size_t)bc * 16384;

    const float a0 = w_s_from_d[0];
    const float a1 = w_s_from_d[1];
    const float wp = softplusf(w_prop[0]);
    const float rwp1 = fastrcp(wp + 1.0f);

    // ---------------- stage BC: pair units (34 rows x 18 pairs = 612) ----------------
    #pragma unroll
    for (int it = 0; it < 2; ++it) {
        int unit = tid + 512 * it;
        if (unit < 612) {
            int a  = unit / 18;              // x-row 0..33
            int k  = unit - 18 * a;          // pair 0..17
            int m  = mB + a;
            int nL = nB0 + 2 * k;            // even; pair covers n = nL, nL+1
            int Lb = 2 * k + 1;              // lx col of nL

            if (m < 0 || m > 127 || nL < 0 || nL > 126) {
                lx1[a][Lb] = 0.f; lx1[a][Lb + 1] = 0.f;
                lx2[a][Lb] = 0.f; lx2[a][Lb + 1] = 0.f;
            } else {
                int cb = 2 * nL;             // multiple of 4
                int c_lo = (cb - 1 < 0) ? 0 : cb - 1;
                int c_hi = (cb + 4 > 255) ? 255 : cb + 4;
                bool has_lo = (nL >= 1);
                bool has_hi = (nL <= 125);
                int r0 = 2 * m - 1;

                float bA1 = NEG_INF, dA1 = 0.f, cA1 = 0.f;
                float bA2 = NEG_INF, dA2 = 0.f, cA2 = 0.f;
                float bB1 = NEG_INF, dB1 = 0.f, cB1 = 0.f;
                float bB2 = NEG_INF, dB2 = 0.f, cB2 = 0.f;

                #pragma unroll
                for (int kh = 0; kh < 4; ++kh) {
                    int r  = r0 + kh;
                    int rl = r < 0 ? 0 : (r > 255 ? 255 : r);
                    bool rv = (r >= 0) && (r < 256);
                    const float* drow = dp  + rl * 256;
                    const float* crow = cdp + rl * 256;
                    float4 d4 = *(const float4*)(drow + cb);
                    float4 c4 = *(const float4*)(crow + cb);
                    float wd[6] = { drow[c_lo], d4.x, d4.y, d4.z, d4.w, drow[c_hi] };
                    float wc[6] = { crow[c_lo], c4.x, c4.y, c4.z, c4.w, crow[c_hi] };
                    bool  mv[6] = { rv && has_lo, rv, rv, rv, rv, rv && has_hi };
                    #pragma unroll
                    for (int idx = 0; idx < 6; ++idx) {
                        float v1 = mv[idx] ? wd[idx] * wc[idx]          : NEG_INF;
                        float v2 = mv[idx] ? wc[idx] / (wd[idx] + EPSF) : NEG_INF;  // EXACT div
                        if (idx <= 3) {      // cell A: window cols cb-1 .. cb+2
                            bool u1 = v1 > bA1;
                            bA1 = u1 ? v1 : bA1; dA1 = u1 ? wd[idx] : dA1; cA1 = u1 ? wc[idx] : cA1;
                            bool u2 = v2 > bA2;
                            bA2 = u2 ? v2 : bA2; dA2 = u2 ? wd[idx] : dA2; cA2 = u2 ? wc[idx] : cA2;
                        }
                        if (idx >= 2) {      // cell B: window cols cb+1 .. cb+4
                            bool u1 = v1 > bB1;
                            bB1 = u1 ? v1 : bB1; dB1 = u1 ? wd[idx] : dB1; cB1 = u1 ? wc[idx] : cB1;
                            bool u2 = v2 > bB2;
                            bB2 = u2 ? v2 : bB2; dB2 = u2 ? wd[idx] : dB2; cB2 = u2 ? wc[idx] : cB2;
                        }
                    }
                }

                float2 sv2  = *(const float2*)(sp  + m * 128 + nL);
                float2 csv2 = *(const float2*)(csp + m * 128 + nL);

                float mA    = fabsf(dA2 * fastrcp(dA1 + EPSF));
                float sfdA  = (1.0f - a0 - a1) * mA + a0 * mA * mA + a1 * mA * mA * mA;
                float csfdA = cA1 * cA2;
                float denA  = wp * csv2.x + csfdA;
                float spA   = (wp * csv2.x * sv2.x + csfdA * sfdA) * fastrcp(denA + EPSF);
                float cpA   = denA * rwp1;

                float mB_   = fabsf(dB2 * fastrcp(dB1 + EPSF));
                float sfdB  = (1.0f - a0 - a1) * mB_ + a0 * mB_ * mB_ + a1 * mB_ * mB_ * mB_;
                float csfdB = cB1 * cB2;
                float denB  = wp * csv2.y + csfdB;
                float spB   = (wp * csv2.y * sv2.y + csfdB * sfdB) * fastrcp(denB + EPSF);
                float cpB   = denB * rwp1;

                lx1[a][Lb]     = cpA * spA;
                lx1[a][Lb + 1] = cpB * spB;
                lx2[a][Lb]     = cpA;
                lx2[a][Lb + 1] = cpB;
            }
        }
    }
    __syncthreads();

    // ---------------- stage D: deconv + epilogue (8 outputs/thread) ----------------
    int ii = tid >> 3, jq = tid & 7;     // ii 0..63, jq 0..7
    int i  = ib + ii;
    int u0 = (i + 1) & 1;
    int m0 = (i + 1 - u0) >> 1;
    int pr0 = m0 - mB;                   // 1..33
    int pr1 = pr0 - 1;                   // 0..32
    float rv0 = (m0 <= 127) ? 1.f : 0.f;
    float rv1 = (m0 >= 1)   ? 1.f : 0.f;

    float wA0 = sws[u0*4 + 0], wA1 = sws[u0*4 + 1], wA2 = sws[u0*4 + 2], wA3 = sws[u0*4 + 3];
    float wC0 = sws[(u0+2)*4 + 0], wC1 = sws[(u0+2)*4 + 1], wC2 = sws[(u0+2)*4 + 2], wC3 = sws[(u0+2)*4 + 3];
    float bv  = bias[c];

    int Lr = 4 * jq + 2;                 // read base: cols Lr..Lr+5  (float2 + float4)
    float r1a[6], r1b[6], r2a[6], r2b[6];
    {
        float2 t2 = *(const float2*)&lx1[pr0][Lr];
        float4 t4 = *(const float4*)&lx1[pr0][Lr + 2];
        r1a[0]=t2.x; r1a[1]=t2.y; r1a[2]=t4.x; r1a[3]=t4.y; r1a[4]=t4.z; r1a[5]=t4.w;
    }
    {
        float2 t2 = *(const float2*)&lx1[pr1][Lr];
        float4 t4 = *(const float4*)&lx1[pr1][Lr + 2];
        r1b[0]=t2.x; r1b[1]=t2.y; r1b[2]=t4.x; r1b[3]=t4.y; r1b[4]=t4.z; r1b[5]=t4.w;
    }
    {
        float2 t2 = *(const float2*)&lx2[pr0][Lr];
        float4 t4 = *(const float4*)&lx2[pr0][Lr + 2];
        r2a[0]=t2.x; r2a[1]=t2.y; r2a[2]=t4.x; r2a[3]=t4.y; r2a[4]=t4.z; r2a[5]=t4.w;
    }
    {
        float2 t2 = *(const float2*)&lx2[pr1][Lr];
        float4 t4 = *(const float4*)&lx2[pr1][Lr + 2];
        r2b[0]=t2.x; r2b[1]=t2.y; r2b[2]=t4.x; r2b[3]=t4.y; r2b[4]=t4.z; r2b[5]=t4.w;
    }

    int n0b = (jb >> 1) + 4 * jq;
    size_t orow = (size_t)bc * 65536 + (size_t)i * 256 + jb + 8 * jq;

    float so[4], co[4];
    #pragma unroll
    for (int e = 0; e < 8; ++e) {
        const int v0 = (e + 1) & 1;
        const int hi = 1 + ((e + 1) >> 1);
        const int lo = hi - 1;
        float swa = v0 ? wA1 : wA0;       // (u0,   v0)
        float swb = v0 ? wA3 : wA2;       // (u0,   v0+2)
        float swc = v0 ? wC1 : wC0;       // (u0+2, v0)
        float swd = v0 ? wC3 : wC2;       // (u0+2, v0+2)

        float nom = swa*r1a[hi] + swb*r1a[lo] + swc*r1b[hi] + swd*r1b[lo];
        float den = swa*r2a[hi] + swb*r2a[lo] + swc*r2b[hi] + swd*r2b[lo];

        int n0 = n0b + ((e + 1) >> 1);
        float nvh = (n0 <= 127) ? 1.f : 0.f;
        float nvl = (n0 >= 1)   ? 1.f : 0.f;
        float cden = rv0 * (swa*nvh + swb*nvl) + rv1 * (swc*nvh + swd*nvl);

        so[e & 3] = nom * fastrcp(den + EPSF) + bv;
        co[e & 3] = den * fastrcp(cden);
        if ((e & 3) == 3) {
            *(float4*)(s_out  + orow + (e - 3)) = make_float4(so[0], so[1], so[2], so[3]);
            *(float4*)(cs_out + orow + (e - 3)) = make_float4(co[0], co[1], co[2], co[3]);
        }
    }
}

extern "C" void kernel_launch(void* const* d_in, const int* in_sizes, int n_in,
                              void* d_out, int out_size, void* d_ws, size_t ws_size,
                              hipStream_t stream) {
    const float* d    = (const float*)d_in[0];
    const float* cd   = (const float*)d_in[1];
    const float* s    = (const float*)d_in[2];
    const float* cs   = (const float*)d_in[3];
    const float* wsd  = (const float*)d_in[4];
    const float* wpr  = (const float*)d_in[5];
    const float* spw  = (const float*)d_in[6];
    const float* bias = (const float*)d_in[7];

    float* out  = (float*)d_out;
    float* s_o  = out;
    float* cs_o = out + (size_t)4 * 16 * 256 * 256;

    // 64 planes x 16 tiles (4x4 of 64x64 outputs) = 1024 blocks x 512 threads
    fused_sndeconv<<<1024, 512, 0, stream>>>(d, cd, s, cs, wsd, wpr, spw, bias, s_o, cs_o);
}

// Round 7
// 34.083 us; speedup vs baseline: 1.7035x; 1.7035x over previous
//
#include <hip/hip_runtime.h>
#include <math.h>

#define EPSF 1e-20f
#define NEG_INF (-INFINITY)

__device__ __forceinline__ float softplusf(float x) {
    return fmaxf(x, 0.0f) + log1pf(expf(-fabsf(x)));
}
// fast reciprocal (v_rcp_f32) — ONLY for tolerance-protected epilogue math,
// never for argmax comparison values.
__device__ __forceinline__ float fastrcp(float x) {
    return __builtin_amdgcn_rcpf(x);
}

// One block = 64x64 output tile of one (b,c) plane; 1024 blocks x 512 threads.
// launch_bounds(512,4): VGPR cap 128 — (512,8) forced a 64-reg cap and spilled
// to scratch (+115 MB HBM traffic, round 6). 4 waves/EU = 16 waves/CU.
// Stage BC: per-thread x-cell PAIR: dual argmax over shared 4x6 window +
//           propagation math -> lx LDS (no W stage, one barrier).
// Stage D : 4-tap transposed depthwise conv + fused epilogue.
__global__ __launch_bounds__(512, 4) void fused_sndeconv(
    const float* __restrict__ d, const float* __restrict__ cd,
    const float* __restrict__ s, const float* __restrict__ cs,
    const float* __restrict__ w_s_from_d, const float* __restrict__ w_prop,
    const float* __restrict__ spatial_weight, const float* __restrict__ bias,
    float* __restrict__ s_out, float* __restrict__ cs_out)
{
    __shared__ float lx1[34][40];        // x1 tile, col L' = n - nB0 + 1; 5.4 KB
    __shared__ float lx2[34][40];        // x2 tile; 5.4 KB
    __shared__ float sws[16];

    const int tid = threadIdx.x;
    const int blk = blockIdx.x;
    const int bc  = blk >> 4;            // plane 0..63
    const int tl  = blk & 15;
    const int ty  = tl >> 2;             // 0..3 (64-row bands)
    const int tx  = tl & 3;              // 0..3 (64-col bands)
    const int c   = bc & 15;

    const int ib  = ty << 6;             // output row base
    const int jb  = tx << 6;             // output col base
    const int mB  = (ib >> 1) - 1;       // x-row base (34 rows: mB..mB+33)
    const int nB0 = (jb >> 1) - 2;       // even x-col pair base

    if (tid < 16) sws[tid] = softplusf(spatial_weight[c * 16 + tid]);

    const float* dp  = d  + (size_t)bc * 65536;
    const float* cdp = cd + (size_t)bc * 65536;
    const float* sp  = s  + (size_t)bc * 16384;
    const float* csp = cs + (size_t)bc * 16384;

    const float a0 = w_s_from_d[0];
    const float a1 = w_s_from_d[1];
    const float wp = softplusf(w_prop[0]);
    const float rwp1 = fastrcp(wp + 1.0f);

    // ---------------- stage BC: pair units (34 rows x 18 pairs = 612) ----------------
    #pragma unroll
    for (int it = 0; it < 2; ++it) {
        int unit = tid + 512 * it;
        if (unit < 612) {
            int a  = unit / 18;              // x-row 0..33
            int k  = unit - 18 * a;          // pair 0..17
            int m  = mB + a;
            int nL = nB0 + 2 * k;            // even; pair covers n = nL, nL+1
            int Lb = 2 * k + 1;              // lx col of nL

            if (m < 0 || m > 127 || nL < 0 || nL > 126) {
                lx1[a][Lb] = 0.f; lx1[a][Lb + 1] = 0.f;
                lx2[a][Lb] = 0.f; lx2[a][Lb + 1] = 0.f;
            } else {
                int cb = 2 * nL;             // multiple of 4
                int c_lo = (cb - 1 < 0) ? 0 : cb - 1;
                int c_hi = (cb + 4 > 255) ? 255 : cb + 4;
                bool has_lo = (nL >= 1);
                bool has_hi = (nL <= 125);
                int r0 = 2 * m - 1;

                float bA1 = NEG_INF, dA1 = 0.f, cA1 = 0.f;
                float bA2 = NEG_INF, dA2 = 0.f, cA2 = 0.f;
                float bB1 = NEG_INF, dB1 = 0.f, cB1 = 0.f;
                float bB2 = NEG_INF, dB2 = 0.f, cB2 = 0.f;

                #pragma unroll
                for (int kh = 0; kh < 4; ++kh) {
                    int r  = r0 + kh;
                    int rl = r < 0 ? 0 : (r > 255 ? 255 : r);
                    bool rv = (r >= 0) && (r < 256);
                    const float* drow = dp  + rl * 256;
                    const float* crow = cdp + rl * 256;
                    float4 d4 = *(const float4*)(drow + cb);
                    float4 c4 = *(const float4*)(crow + cb);
                    float wd[6] = { drow[c_lo], d4.x, d4.y, d4.z, d4.w, drow[c_hi] };
                    float wc[6] = { crow[c_lo], c4.x, c4.y, c4.z, c4.w, crow[c_hi] };
                    bool  mv[6] = { rv && has_lo, rv, rv, rv, rv, rv && has_hi };
                    #pragma unroll
                    for (int idx = 0; idx < 6; ++idx) {
                        float v1 = mv[idx] ? wd[idx] * wc[idx]          : NEG_INF;
                        float v2 = mv[idx] ? wc[idx] / (wd[idx] + EPSF) : NEG_INF;  // EXACT div
                        if (idx <= 3) {      // cell A: window cols cb-1 .. cb+2
                            bool u1 = v1 > bA1;
                            bA1 = u1 ? v1 : bA1; dA1 = u1 ? wd[idx] : dA1; cA1 = u1 ? wc[idx] : cA1;
                            bool u2 = v2 > bA2;
                            bA2 = u2 ? v2 : bA2; dA2 = u2 ? wd[idx] : dA2; cA2 = u2 ? wc[idx] : cA2;
                        }
                        if (idx >= 2) {      // cell B: window cols cb+1 .. cb+4
                            bool u1 = v1 > bB1;
                            bB1 = u1 ? v1 : bB1; dB1 = u1 ? wd[idx] : dB1; cB1 = u1 ? wc[idx] : cB1;
                            bool u2 = v2 > bB2;
                            bB2 = u2 ? v2 : bB2; dB2 = u2 ? wd[idx] : dB2; cB2 = u2 ? wc[idx] : cB2;
                        }
                    }
                }

                float2 sv2  = *(const float2*)(sp  + m * 128 + nL);
                float2 csv2 = *(const float2*)(csp + m * 128 + nL);

                float mA    = fabsf(dA2 * fastrcp(dA1 + EPSF));
                float sfdA  = (1.0f - a0 - a1) * mA + a0 * mA * mA + a1 * mA * mA * mA;
                float csfdA = cA1 * cA2;
                float denA  = wp * csv2.x + csfdA;
                float spA   = (wp * csv2.x * sv2.x + csfdA * sfdA) * fastrcp(denA + EPSF);
                float cpA   = denA * rwp1;

                float mB_   = fabsf(dB2 * fastrcp(dB1 + EPSF));
                float sfdB  = (1.0f - a0 - a1) * mB_ + a0 * mB_ * mB_ + a1 * mB_ * mB_ * mB_;
                float csfdB = cB1 * cB2;
                float denB  = wp * csv2.y + csfdB;
                float spB   = (wp * csv2.y * sv2.y + csfdB * sfdB) * fastrcp(denB + EPSF);
                float cpB   = denB * rwp1;

                lx1[a][Lb]     = cpA * spA;
                lx1[a][Lb + 1] = cpB * spB;
                lx2[a][Lb]     = cpA;
                lx2[a][Lb + 1] = cpB;
            }
        }
    }
    __syncthreads();

    // ---------------- stage D: deconv + epilogue (8 outputs/thread) ----------------
    int ii = tid >> 3, jq = tid & 7;     // ii 0..63, jq 0..7
    int i  = ib + ii;
    int u0 = (i + 1) & 1;
    int m0 = (i + 1 - u0) >> 1;
    int pr0 = m0 - mB;                   // 1..33
    int pr1 = pr0 - 1;                   // 0..32
    float rv0 = (m0 <= 127) ? 1.f : 0.f;
    float rv1 = (m0 >= 1)   ? 1.f : 0.f;

    float wA0 = sws[u0*4 + 0], wA1 = sws[u0*4 + 1], wA2 = sws[u0*4 + 2], wA3 = sws[u0*4 + 3];
    float wC0 = sws[(u0+2)*4 + 0], wC1 = sws[(u0+2)*4 + 1], wC2 = sws[(u0+2)*4 + 2], wC3 = sws[(u0+2)*4 + 3];
    float bv  = bias[c];

    int Lr = 4 * jq + 2;                 // read base: cols Lr..Lr+5  (float2 + float4)
    float r1a[6], r1b[6], r2a[6], r2b[6];
    {
        float2 t2 = *(const float2*)&lx1[pr0][Lr];
        float4 t4 = *(const float4*)&lx1[pr0][Lr + 2];
        r1a[0]=t2.x; r1a[1]=t2.y; r1a[2]=t4.x; r1a[3]=t4.y; r1a[4]=t4.z; r1a[5]=t4.w;
    }
    {
        float2 t2 = *(const float2*)&lx1[pr1][Lr];
        float4 t4 = *(const float4*)&lx1[pr1][Lr + 2];
        r1b[0]=t2.x; r1b[1]=t2.y; r1b[2]=t4.x; r1b[3]=t4.y; r1b[4]=t4.z; r1b[5]=t4.w;
    }
    {
        float2 t2 = *(const float2*)&lx2[pr0][Lr];
        float4 t4 = *(const float4*)&lx2[pr0][Lr + 2];
        r2a[0]=t2.x; r2a[1]=t2.y; r2a[2]=t4.x; r2a[3]=t4.y; r2a[4]=t4.z; r2a[5]=t4.w;
    }
    {
        float2 t2 = *(const float2*)&lx2[pr1][Lr];
        float4 t4 = *(const float4*)&lx2[pr1][Lr + 2];
        r2b[0]=t2.x; r2b[1]=t2.y; r2b[2]=t4.x; r2b[3]=t4.y; r2b[4]=t4.z; r2b[5]=t4.w;
    }

    int n0b = (jb >> 1) + 4 * jq;
    size_t orow = (size_t)bc * 65536 + (size_t)i * 256 + jb + 8 * jq;

    float so[4], co[4];
    #pragma unroll
    for (int e = 0; e < 8; ++e) {
        const int v0 = (e + 1) & 1;
        const int hi = 1 + ((e + 1) >> 1);
        const int lo = hi - 1;
        float swa = v0 ? wA1 : wA0;       // (u0,   v0)
        float swb = v0 ? wA3 : wA2;       // (u0,   v0+2)
        float swc = v0 ? wC1 : wC0;       // (u0+2, v0)
        float swd = v0 ? wC3 : wC2;       // (u0+2, v0+2)

        float nom = swa*r1a[hi] + swb*r1a[lo] + swc*r1b[hi] + swd*r1b[lo];
        float den = swa*r2a[hi] + swb*r2a[lo] + swc*r2b[hi] + swd*r2b[lo];

        int n0 = n0b + ((e + 1) >> 1);
        float nvh = (n0 <= 127) ? 1.f : 0.f;
        float nvl = (n0 >= 1)   ? 1.f : 0.f;
        float cden = rv0 * (swa*nvh + swb*nvl) + rv1 * (swc*nvh + swd*nvl);

        so[e & 3] = nom * fastrcp(den + EPSF) + bv;
        co[e & 3] = den * fastrcp(cden);
        if ((e & 3) == 3) {
            *(float4*)(s_out  + orow + (e - 3)) = make_float4(so[0], so[1], so[2], so[3]);
            *(float4*)(cs_out + orow + (e - 3)) = make_float4(co[0], co[1], co[2], co[3]);
        }
    }
}

extern "C" void kernel_launch(void* const* d_in, const int* in_sizes, int n_in,
                              void* d_out, int out_size, void* d_ws, size_t ws_size,
                              hipStream_t stream) {
    const float* d    = (const float*)d_in[0];
    const float* cd   = (const float*)d_in[1];
    const float* s    = (const float*)d_in[2];
    const float* cs   = (const float*)d_in[3];
    const float* wsd  = (const float*)d_in[4];
    const float* wpr  = (const float*)d_in[5];
    const float* spw  = (const float*)d_in[6];
    const float* bias = (const float*)d_in[7];

    float* out  = (float*)d_out;
    float* s_o  = out;
    float* cs_o = out + (size_t)4 * 16 * 256 * 256;

    // 64 planes x 16 tiles (4x4 of 64x64 outputs) = 1024 blocks x 512 threads
    fused_sndeconv<<<1024, 512, 0, stream>>>(d, cd, s, cs, wsd, wpr, spw, bias, s_o, cs_o);
}

// Round 8
// 28.962 us; speedup vs baseline: 2.0048x; 1.1768x over previous
//
#include <hip/hip_runtime.h>
#include <math.h>

#define EPSF 1e-20f
#define NEG_INF (-INFINITY)

__device__ __forceinline__ float softplusf(float x) {
    return fmaxf(x, 0.0f) + log1pf(expf(-fabsf(x)));
}
// fast reciprocal (v_rcp_f32) — ONLY for tolerance-protected epilogue math,
// never for argmax comparison values.
__device__ __forceinline__ float fastrcp(float x) {
    return __builtin_amdgcn_rcpf(x);
}

// One block = 32x64 output tile of one (b,c) plane. 2048 blocks x 256 threads.
// Stage B: horizontal 4-col dual argmax per (input row, x-col); stores winner
//          VALUES with 20B payload: W4=(d1,c1,v2,d2), W1=(c2). v1 is NOT
//          stored — recomputed as d1*c1 in stage C (bit-exact same product).
//          LDS 36.3->30.4 KB => 5 blocks/CU (was 4).
// Stage C: vertical 4-row combine (flat-order strict >) + propagation -> lx.
// Stage D: 4-tap transposed depthwise conv + fused epilogue.
__global__ __launch_bounds__(256) void fused_sndeconv(
    const float* __restrict__ d, const float* __restrict__ cd,
    const float* __restrict__ s, const float* __restrict__ cs,
    const float* __restrict__ w_s_from_d, const float* __restrict__ w_prop,
    const float* __restrict__ spatial_weight, const float* __restrict__ bias,
    float* __restrict__ s_out, float* __restrict__ cs_out)
{
    __shared__ float4 W4[38][34];        // (d1, c1, v2, d2)  20.2 KB
    __shared__ float  W1[38][34];        // (c2)               5.0 KB
    __shared__ float  lx1[18][36];       //  2.6 KB
    __shared__ float  lx2[18][36];       //  2.6 KB
    __shared__ float  sws[16];

    const int tid = threadIdx.x;
    const int blk = blockIdx.x;
    const int bc  = blk >> 5;            // plane 0..63
    const int tl  = blk & 31;
    const int by  = tl >> 2;             // 0..7  (32-row bands)
    const int bx  = tl & 3;              // 0..3  (64-col bands)
    const int c   = bc & 15;

    const int ib = by << 5;              // output row base
    const int jb = bx << 6;              // output col base
    const int mB = (ib >> 1) - 1;        // x-row base (18 rows)
    const int nB = (jb >> 1) - 1;        // x-col base (34 cols)
    const int rB = 2 * mB - 1;           // input row base (38 rows)
    const int cB = 2 * nB - 1;           // input col base (odd)

    if (tid < 16) sws[tid] = softplusf(spatial_weight[c * 16 + tid]);

    const float* dp  = d  + (size_t)bc * 65536;
    const float* cdp = cd + (size_t)bc * 65536;
    const float* sp  = s  + (size_t)bc * 16384;
    const float* csp = cs + (size_t)bc * 16384;

    const float a0 = w_s_from_d[0];
    const float a1 = w_s_from_d[1];
    const float wp = softplusf(w_prop[0]);
    const float rwp1 = fastrcp(wp + 1.0f);

    // ---------------- stage B: horizontal window argmax ----------------
    #pragma unroll
    for (int it = 0; it < 6; ++it) {
        int unit = tid + 256 * it;
        if (unit < 1292) {
            int wr = unit / 34;
            int wn = unit - wr * 34;
            int r  = rB + wr;
            int cb = cB + 2 * wn;                    // odd
            bool rv = (r >= 0) && (r < 256);
            int  rl = r < 0 ? 0 : (r > 255 ? 255 : r);
            const float* drow = dp  + rl * 256;
            const float* crow = cdp + rl * 256;

            int c0 = cb < 0 ? 0 : cb;
            int c3 = (cb + 3 > 255) ? 255 : cb + 3;
            int cm = cb + 1; cm = cm < 0 ? 0 : (cm > 254 ? 254 : cm);  // even
            float2 dm = *(const float2*)(drow + cm);
            float2 cc = *(const float2*)(crow + cm);
            float wd[4] = { drow[c0], dm.x, dm.y, drow[c3] };
            float wc[4] = { crow[c0], cc.x, cc.y, crow[c3] };

            // chain1 payload init: (-inf, 1) so recomputed v1 = -inf can't win
            float b1 = NEG_INF, d1 = NEG_INF, c1 = 1.0f;
            float b2 = NEG_INF, d2 = 0.f,     c2 = 0.f;
            #pragma unroll
            for (int k = 0; k < 4; ++k) {
                int  ck = cb + k;
                bool mv = rv && (ck >= 0) && (ck < 256);
                float v1 = mv ? wd[k] * wc[k]          : NEG_INF;
                float v2 = mv ? wc[k] / (wd[k] + EPSF) : NEG_INF;  // EXACT div
                bool t1 = v1 > b1;
                b1 = t1 ? v1 : b1; d1 = t1 ? wd[k] : d1; c1 = t1 ? wc[k] : c1;
                bool t2 = v2 > b2;
                b2 = t2 ? v2 : b2; d2 = t2 ? wd[k] : d2; c2 = t2 ? wc[k] : c2;
            }
            W4[wr][wn] = make_float4(d1, c1, b2, d2);
            W1[wr][wn] = c2;
        }
    }
    __syncthreads();

    // ---------------- stage C: vertical combine + prop math ----------------
    #pragma unroll
    for (int it = 0; it < 3; ++it) {
        int unit = tid + 256 * it;
        if (unit < 612) {
            int cmr = unit / 34;
            int cn  = unit - cmr * 34;
            int m   = mB + cmr;
            int n   = nB + cn;
            if (m < 0 || m > 127 || n < 0 || n > 127) {
                lx1[cmr][cn] = 0.f;
                lx2[cmr][cn] = 0.f;
            } else {
                float4 a4 = W4[2 * cmr + 0][cn];
                float  e1 = W1[2 * cmr + 0][cn];
                float d1 = a4.x, c1 = a4.y, b2 = a4.z, d2 = a4.w, c2 = e1;
                float b1 = d1 * c1;                  // recomputed v1 (bit-exact)
                #pragma unroll
                for (int k = 1; k < 4; ++k) {
                    float4 w4 = W4[2 * cmr + k][cn];
                    float  w1 = W1[2 * cmr + k][cn];
                    float v1 = w4.x * w4.y;
                    bool t1 = v1 > b1;
                    b1 = t1 ? v1 : b1; d1 = t1 ? w4.x : d1; c1 = t1 ? w4.y : c1;
                    bool t2 = w4.z > b2;
                    b2 = t2 ? w4.z : b2; d2 = t2 ? w4.w : d2; c2 = t2 ? w1 : c2;
                }

                float mm_  = fabsf(d2 * fastrcp(d1 + EPSF));
                float sfd  = (1.0f - a0 - a1) * mm_ + a0 * mm_ * mm_ + a1 * mm_ * mm_ * mm_;
                float csfd = c1 * c2;
                float sv   = sp[m * 128 + n];
                float csv  = csp[m * 128 + n];
                float den  = wp * csv + csfd;
                float spv  = (wp * csv * sv + csfd * sfd) * fastrcp(den + EPSF);
                float cp   = den * rwp1;
                lx1[cmr][cn] = cp * spv;
                lx2[cmr][cn] = cp;
            }
        }
    }
    __syncthreads();

    // ---------------- stage D: deconv + epilogue (8 outputs/thread) ----------------
    int ii = tid >> 3, jq = tid & 7;
    int i  = ib + ii;
    int u0 = (i + 1) & 1;
    int m0 = (i + 1 - u0) >> 1;
    int pr0 = m0 - mB;                    // 1..17
    int pr1 = pr0 - 1;                    // 0..16
    float rv0 = (m0 <= 127) ? 1.f : 0.f;
    float rv1 = (m0 >= 1)   ? 1.f : 0.f;

    float wA0 = sws[u0*4 + 0], wA1 = sws[u0*4 + 1], wA2 = sws[u0*4 + 2], wA3 = sws[u0*4 + 3];
    float wC0 = sws[(u0+2)*4 + 0], wC1 = sws[(u0+2)*4 + 1], wC2 = sws[(u0+2)*4 + 2], wC3 = sws[(u0+2)*4 + 3];
    float bv  = bias[c];

    int bb = 4 * jq;
    float r1a[6], r1b[6], r2a[6], r2b[6];
    {
        const float* p = &lx1[pr0][bb];
        float4 t4 = *(const float4*)p;  float2 t2 = *(const float2*)(p + 4);
        r1a[0]=t4.x; r1a[1]=t4.y; r1a[2]=t4.z; r1a[3]=t4.w; r1a[4]=t2.x; r1a[5]=t2.y;
    }
    {
        const float* p = &lx1[pr1][bb];
        float4 t4 = *(const float4*)p;  float2 t2 = *(const float2*)(p + 4);
        r1b[0]=t4.x; r1b[1]=t4.y; r1b[2]=t4.z; r1b[3]=t4.w; r1b[4]=t2.x; r1b[5]=t2.y;
    }
    {
        const float* p = &lx2[pr0][bb];
        float4 t4 = *(const float4*)p;  float2 t2 = *(const float2*)(p + 4);
        r2a[0]=t4.x; r2a[1]=t4.y; r2a[2]=t4.z; r2a[3]=t4.w; r2a[4]=t2.x; r2a[5]=t2.y;
    }
    {
        const float* p = &lx2[pr1][bb];
        float4 t4 = *(const float4*)p;  float2 t2 = *(const float2*)(p + 4);
        r2b[0]=t4.x; r2b[1]=t4.y; r2b[2]=t4.z; r2b[3]=t4.w; r2b[4]=t2.x; r2b[5]=t2.y;
    }

    int n0b = (jb >> 1) + 4 * jq;
    size_t orow = (size_t)bc * 65536 + (size_t)i * 256 + jb + 8 * jq;

    float so[4], co[4];
    #pragma unroll
    for (int e = 0; e < 8; ++e) {
        const int v0 = (e + 1) & 1;
        const int hi = 1 + ((e + 1) >> 1);
        const int lo = hi - 1;
        float swa = v0 ? wA1 : wA0;       // (u0,   v0)
        float swb = v0 ? wA3 : wA2;       // (u0,   v0+2)
        float swc = v0 ? wC1 : wC0;       // (u0+2, v0)
        float swd = v0 ? wC3 : wC2;       // (u0+2, v0+2)

        float nom = swa*r1a[hi] + swb*r1a[lo] + swc*r1b[hi] + swd*r1b[lo];
        float den = swa*r2a[hi] + swb*r2a[lo] + swc*r2b[hi] + swd*r2b[lo];

        int n0 = n0b + ((e + 1) >> 1);
        float nvh = (n0 <= 127) ? 1.f : 0.f;
        float nvl = (n0 >= 1)   ? 1.f : 0.f;
        float cden = rv0 * (swa*nvh + swb*nvl) + rv1 * (swc*nvh + swd*nvl);

        so[e & 3] = nom * fastrcp(den + EPSF) + bv;
        co[e & 3] = den * fastrcp(cden);
        if ((e & 3) == 3) {
            *(float4*)(s_out  + orow + (e - 3)) = make_float4(so[0], so[1], so[2], so[3]);
            *(float4*)(cs_out + orow + (e - 3)) = make_float4(co[0], co[1], co[2], co[3]);
        }
    }
}

extern "C" void kernel_launch(void* const* d_in, const int* in_sizes, int n_in,
                              void* d_out, int out_size, void* d_ws, size_t ws_size,
                              hipStream_t stream) {
    const float* d    = (const float*)d_in[0];
    const float* cd   = (const float*)d_in[1];
    const float* s    = (const float*)d_in[2];
    const float* cs   = (const float*)d_in[3];
    const float* wsd  = (const float*)d_in[4];
    const float* wpr  = (const float*)d_in[5];
    const float* spw  = (const float*)d_in[6];
    const float* bias = (const float*)d_in[7];

    float* out  = (float*)d_out;
    float* s_o  = out;
    float* cs_o = out + (size_t)4 * 16 * 256 * 256;

    // 64 planes x 32 tiles (8x4 of 32x64 outputs) = 2048 blocks
    fused_sndeconv<<<2048, 256, 0, stream>>>(d, cd, s, cs, wsd, wpr, spw, bias, s_o, cs_o);
}

// Round 9
// 27.428 us; speedup vs baseline: 2.1169x; 1.0559x over previous
//
#include <hip/hip_runtime.h>
#include <math.h>

#define EPSF 1e-20f
#define NEG_INF (-INFINITY)

__device__ __forceinline__ float softplusf(float x) {
    return fmaxf(x, 0.0f) + log1pf(expf(-fabsf(x)));
}
// fast reciprocal (v_rcp_f32) — ONLY for tolerance-protected epilogue math,
// never for argmax comparison values.
__device__ __forceinline__ float fastrcp(float x) {
    return __builtin_amdgcn_rcpf(x);
}

// Issue the 6 global loads for stage-B unit `unit` (must be pre-clamped to
// [0,1291]). Pure loads — no dependent compute, so they pipeline.
__device__ __forceinline__ void issue_unit_loads(
    int unit, const float* __restrict__ dp, const float* __restrict__ cdp,
    int rB, int cB,
    float& d0, float2& d12, float& d3,
    float& c0, float2& c12, float& c3)
{
    int wr = unit / 34;
    int wn = unit - wr * 34;
    int r  = rB + wr;
    int rl = r < 0 ? 0 : (r > 255 ? 255 : r);
    int cb = cB + 2 * wn;                      // odd
    int c0i = cb < 0 ? 0 : cb;
    int c3i = (cb + 3 > 255) ? 255 : cb + 3;
    int cmi = cb + 1; cmi = cmi < 0 ? 0 : (cmi > 254 ? 254 : cmi);   // even
    const float* drow = dp  + rl * 256;
    const float* crow = cdp + rl * 256;
    d0  = drow[c0i];
    d12 = *(const float2*)(drow + cmi);
    d3  = drow[c3i];
    c0  = crow[c0i];
    c12 = *(const float2*)(crow + cmi);
    c3  = crow[c3i];
}

// One block = 32x64 output tile of one (b,c) plane. 2048 blocks x 256 threads.
// Stage B: horizontal 4-col dual argmax per (input row, x-col); SOFTWARE
//          PIPELINED: unit it+1's loads issue before unit it's compute
//          (register double-buffer, compile-time indices). Payload 20B:
//          W4=(d1,c1,v2,d2), W1=(c2); v1 recomputed as d1*c1 in stage C.
// Stage C: vertical 4-row combine (flat-order strict >) + propagation -> lx.
// Stage D: 4-tap transposed depthwise conv + fused epilogue.
__global__ __launch_bounds__(256, 4) void fused_sndeconv(
    const float* __restrict__ d, const float* __restrict__ cd,
    const float* __restrict__ s, const float* __restrict__ cs,
    const float* __restrict__ w_s_from_d, const float* __restrict__ w_prop,
    const float* __restrict__ spatial_weight, const float* __restrict__ bias,
    float* __restrict__ s_out, float* __restrict__ cs_out)
{
    __shared__ float4 W4[38][34];        // (d1, c1, v2, d2)  20.2 KB
    __shared__ float  W1[38][34];        // (c2)               5.0 KB
    __shared__ float  lx1[18][36];       //  2.6 KB
    __shared__ float  lx2[18][36];       //  2.6 KB
    __shared__ float  sws[16];

    const int tid = threadIdx.x;
    const int blk = blockIdx.x;
    const int bc  = blk >> 5;            // plane 0..63
    const int tl  = blk & 31;
    const int by  = tl >> 2;             // 0..7  (32-row bands)
    const int bx  = tl & 3;              // 0..3  (64-col bands)
    const int c   = bc & 15;

    const int ib = by << 5;              // output row base
    const int jb = bx << 6;              // output col base
    const int mB = (ib >> 1) - 1;        // x-row base (18 rows)
    const int nB = (jb >> 1) - 1;        // x-col base (34 cols)
    const int rB = 2 * mB - 1;           // input row base (38 rows)
    const int cB = 2 * nB - 1;           // input col base (odd)

    if (tid < 16) sws[tid] = softplusf(spatial_weight[c * 16 + tid]);

    const float* dp  = d  + (size_t)bc * 65536;
    const float* cdp = cd + (size_t)bc * 65536;
    const float* sp  = s  + (size_t)bc * 16384;
    const float* csp = cs + (size_t)bc * 16384;

    const float a0 = w_s_from_d[0];
    const float a1 = w_s_from_d[1];
    const float wp = softplusf(w_prop[0]);
    const float rwp1 = fastrcp(wp + 1.0f);

    // ---------------- stage B: pipelined horizontal window argmax ----------------
    {
        float  pd0[2], pd3[2], pc0[2], pc3[2];
        float2 pd12[2], pc12[2];

        // prologue: unit for it=0 (tid < 256 < 1292, no clamp needed)
        issue_unit_loads(tid, dp, cdp, rB, cB,
                         pd0[0], pd12[0], pd3[0], pc0[0], pc12[0], pc3[0]);

        #pragma unroll
        for (int it = 0; it < 6; ++it) {
            const int cur = it & 1;
            const int nxt = cur ^ 1;
            if (it < 5) {                        // compile-time after unroll
                int nu = tid + 256 * (it + 1);
                nu = nu < 1292 ? nu : 1291;      // clamp: safe redundant loads
                issue_unit_loads(nu, dp, cdp, rB, cB,
                                 pd0[nxt], pd12[nxt], pd3[nxt],
                                 pc0[nxt], pc12[nxt], pc3[nxt]);
            }
            int unit = tid + 256 * it;
            if (unit < 1292) {
                int wr = unit / 34;
                int wn = unit - wr * 34;
                int r  = rB + wr;
                int cb = cB + 2 * wn;            // odd
                bool rv = (r >= 0) && (r < 256);

                float wd[4] = { pd0[cur], pd12[cur].x, pd12[cur].y, pd3[cur] };
                float wc[4] = { pc0[cur], pc12[cur].x, pc12[cur].y, pc3[cur] };

                // chain1 payload init: (-inf, 1) so recomputed v1 = -inf can't win
                float b1 = NEG_INF, d1 = NEG_INF, c1 = 1.0f;
                float b2 = NEG_INF, d2 = 0.f,     c2 = 0.f;
                #pragma unroll
                for (int k = 0; k < 4; ++k) {
                    int  ck = cb + k;
                    bool mv = rv && (ck >= 0) && (ck < 256);
                    float v1 = mv ? wd[k] * wc[k]          : NEG_INF;
                    float v2 = mv ? wc[k] / (wd[k] + EPSF) : NEG_INF;  // EXACT div
                    bool t1 = v1 > b1;
                    b1 = t1 ? v1 : b1; d1 = t1 ? wd[k] : d1; c1 = t1 ? wc[k] : c1;
                    bool t2 = v2 > b2;
                    b2 = t2 ? v2 : b2; d2 = t2 ? wd[k] : d2; c2 = t2 ? wc[k] : c2;
                }
                W4[wr][wn] = make_float4(d1, c1, b2, d2);
                W1[wr][wn] = c2;
            }
        }
    }
    __syncthreads();

    // ---------------- stage C: vertical combine + prop math ----------------
    #pragma unroll
    for (int it = 0; it < 3; ++it) {
        int unit = tid + 256 * it;
        if (unit < 612) {
            int cmr = unit / 34;
            int cn  = unit - cmr * 34;
            int m   = mB + cmr;
            int n   = nB + cn;
            if (m < 0 || m > 127 || n < 0 || n > 127) {
                lx1[cmr][cn] = 0.f;
                lx2[cmr][cn] = 0.f;
            } else {
                // issue global loads FIRST (overlap with LDS combine below)
                float sv   = sp[m * 128 + n];
                float csv  = csp[m * 128 + n];

                float4 a4 = W4[2 * cmr + 0][cn];
                float  e1 = W1[2 * cmr + 0][cn];
                float d1 = a4.x, c1 = a4.y, b2 = a4.z, d2 = a4.w, c2 = e1;
                float b1 = d1 * c1;                  // recomputed v1 (bit-exact)
                #pragma unroll
                for (int k = 1; k < 4; ++k) {
                    float4 w4 = W4[2 * cmr + k][cn];
                    float  w1 = W1[2 * cmr + k][cn];
                    float v1 = w4.x * w4.y;
                    bool t1 = v1 > b1;
                    b1 = t1 ? v1 : b1; d1 = t1 ? w4.x : d1; c1 = t1 ? w4.y : c1;
                    bool t2 = w4.z > b2;
                    b2 = t2 ? w4.z : b2; d2 = t2 ? w4.w : d2; c2 = t2 ? w1 : c2;
                }

                float mm_  = fabsf(d2 * fastrcp(d1 + EPSF));
                float sfd  = (1.0f - a0 - a1) * mm_ + a0 * mm_ * mm_ + a1 * mm_ * mm_ * mm_;
                float csfd = c1 * c2;
                float den  = wp * csv + csfd;
                float spv  = (wp * csv * sv + csfd * sfd) * fastrcp(den + EPSF);
                float cp   = den * rwp1;
                lx1[cmr][cn] = cp * spv;
                lx2[cmr][cn] = cp;
            }
        }
    }
    __syncthreads();

    // ---------------- stage D: deconv + epilogue (8 outputs/thread) ----------------
    int ii = tid >> 3, jq = tid & 7;
    int i  = ib + ii;
    int u0 = (i + 1) & 1;
    int m0 = (i + 1 - u0) >> 1;
    int pr0 = m0 - mB;                    // 1..17
    int pr1 = pr0 - 1;                    // 0..16
    float rv0 = (m0 <= 127) ? 1.f : 0.f;
    float rv1 = (m0 >= 1)   ? 1.f : 0.f;

    float wA0 = sws[u0*4 + 0], wA1 = sws[u0*4 + 1], wA2 = sws[u0*4 + 2], wA3 = sws[u0*4 + 3];
    float wC0 = sws[(u0+2)*4 + 0], wC1 = sws[(u0+2)*4 + 1], wC2 = sws[(u0+2)*4 + 2], wC3 = sws[(u0+2)*4 + 3];
    float bv  = bias[c];

    int bb = 4 * jq;
    float r1a[6], r1b[6], r2a[6], r2b[6];
    {
        const float* p = &lx1[pr0][bb];
        float4 t4 = *(const float4*)p;  float2 t2 = *(const float2*)(p + 4);
        r1a[0]=t4.x; r1a[1]=t4.y; r1a[2]=t4.z; r1a[3]=t4.w; r1a[4]=t2.x; r1a[5]=t2.y;
    }
    {
        const float* p = &lx1[pr1][bb];
        float4 t4 = *(const float4*)p;  float2 t2 = *(const float2*)(p + 4);
        r1b[0]=t4.x; r1b[1]=t4.y; r1b[2]=t4.z; r1b[3]=t4.w; r1b[4]=t2.x; r1b[5]=t2.y;
    }
    {
        const float* p = &lx2[pr0][bb];
        float4 t4 = *(const float4*)p;  float2 t2 = *(const float2*)(p + 4);
        r2a[0]=t4.x; r2a[1]=t4.y; r2a[2]=t4.z; r2a[3]=t4.w; r2a[4]=t2.x; r2a[5]=t2.y;
    }
    {
        const float* p = &lx2[pr1][bb];
        float4 t4 = *(const float4*)p;  float2 t2 = *(const float2*)(p + 4);
        r2b[0]=t4.x; r2b[1]=t4.y; r2b[2]=t4.z; r2b[3]=t4.w; r2b[4]=t2.x; r2b[5]=t2.y;
    }

    int n0b = (jb >> 1) + 4 * jq;
    size_t orow = (size_t)bc * 65536 + (size_t)i * 256 + jb + 8 * jq;

    float so[4], co[4];
    #pragma unroll
    for (int e = 0; e < 8; ++e) {
        const int v0 = (e + 1) & 1;
        const int hi = 1 + ((e + 1) >> 1);
        const int lo = hi - 1;
        float swa = v0 ? wA1 : wA0;       // (u0,   v0)
        float swb = v0 ? wA3 : wA2;       // (u0,   v0+2)
        float swc = v0 ? wC1 : wC0;       // (u0+2, v0)
        float swd = v0 ? wC3 : wC2;       // (u0+2, v0+2)

        float nom = swa*r1a[hi] + swb*r1a[lo] + swc*r1b[hi] + swd*r1b[lo];
        float den = swa*r2a[hi] + swb*r2a[lo] + swc*r2b[hi] + swd*r2b[lo];

        int n0 = n0b + ((e + 1) >> 1);
        float nvh = (n0 <= 127) ? 1.f : 0.f;
        float nvl = (n0 >= 1)   ? 1.f : 0.f;
        float cden = rv0 * (swa*nvh + swb*nvl) + rv1 * (swc*nvh + swd*nvl);

        so[e & 3] = nom * fastrcp(den + EPSF) + bv;
        co[e & 3] = den * fastrcp(cden);
        if ((e & 3) == 3) {
            *(float4*)(s_out  + orow + (e - 3)) = make_float4(so[0], so[1], so[2], so[3]);
            *(float4*)(cs_out + orow + (e - 3)) = make_float4(co[0], co[1], co[2], co[3]);
        }
    }
}

extern "C" void kernel_launch(void* const* d_in, const int* in_sizes, int n_in,
                              void* d_out, int out_size, void* d_ws, size_t ws_size,
                              hipStream_t stream) {
    const float* d    = (const float*)d_in[0];
    const float* cd   = (const float*)d_in[1];
    const float* s    = (const float*)d_in[2];
    const float* cs   = (const float*)d_in[3];
    const float* wsd  = (const float*)d_in[4];
    const float* wpr  = (const float*)d_in[5];
    const float* spw  = (const float*)d_in[6];
    const float* bias = (const float*)d_in[7];

    float* out  = (float*)d_out;
    float* s_o  = out;
    float* cs_o = out + (size_t)4 * 16 * 256 * 256;

    // 64 planes x 32 tiles (8x4 of 32x64 outputs) = 2048 blocks
    fused_sndeconv<<<2048, 256, 0, stream>>>(d, cd, s, cs, wsd, wpr, spw, bias, s_o, cs_o);
}